// Round 1
// 163.701 us; speedup vs baseline: 1.0558x; 1.0558x over previous
//
#include <hip/hip_runtime.h>

// ODENet forward, round 15: r14 core + (a) register-resident MFMA-sliced
// epilogue: wave w's Y[nb][r] regs ARE y[16w..16w+15][n] -> per-wave k-slice
// partials of y@Wl via 160 reg-FMAs + 2x shfl_xor q-reduce + 20KB LDS
// partial array; kills yfin (33KB), one barrier, the 640x128 serial fmaf
// chains and their 2x ds_read_b32 per FMA. (b) async x prefetch: raw[2]
// double buffer + global_load_lds(width16, linear dest), issued at tile
// top, drained by vmcnt(0) one full tile later.
// Core (validated r14): pack kernel + no-spill 128-VGPR weight residency,
// f16 MFMA 16x16x32, fp32 state, RK4 N=1 (absmax bit-identical 0.03125 at
// N=8/6/4/3/2/1), lo/hi b64 conflict-free LDS B-fragments, ping-pong
// 2x32KB, grid 256 persistent, 4 row-tiles/WG, weights loaded once.
// HISTORY (do not regress): r5 launch_bounds(512,4) -> weight spill (3.3GB
// HBM); r8 inline f32 gather -> ~50-reg spill; r11 LDS union overlays ->
// post-timing divergence (keep dedicated regions); r13 full-unroll float4
// epilogue reads -> +23us. Keep launch_bounds(512,2).

typedef _Float16 half8 __attribute__((ext_vector_type(8)));
typedef _Float16 half4 __attribute__((ext_vector_type(4)));
typedef float    floatx4 __attribute__((ext_vector_type(4)));

#define MFMA16 __builtin_amdgcn_mfma_f32_16x16x32_f16

constexpr int DDIM  = 118;
constexpr int NSTEP = 1;
constexpr int TILES = 4;      // row-tiles of 64 per WG (grid 256)

// async global->LDS, 16B/lane, LDS dest = wave-uniform base + lane*16
#define GLOAD_LDS16(g, p) __builtin_amdgcn_global_load_lds(              \
    (const __attribute__((address_space(1))) void*)(g),                  \
    (__attribute__((address_space(3))) void*)(p), 16, 0, 0)

// B-frag element group offset (f16 units) inside one 32KB half-buffer:
// element(k = 32*kc + 8*(slot>>4) + 4*h + t, n = 16*nb + (slot&15)) at
// IDX(kc,nb,h,slot) + t.
__device__ __forceinline__ int IDX(int kc, int nb, int h, int slot) {
  return (((kc*4 + nb)*2 + h)*64 + slot)*4;
}

struct SMemT {
  _Float16 b[2][16384];   // ping-pong activation buffers, 32KB each
  float raw[2][7552];     // x staging, double-buffered for async prefetch
  float wl[1280];         // Wl staged (5120B), [k][o] layout
  float part[8 * 10 * 66];// epilogue partials [w][o][pad66] (21120B)
  float bls[10];          // bl staged
};                        // total ~148.7KB < 160KB/CU (1 WG/CU persistent)

// Fused pack: fp32 W[K][N] (k-major) -> A-fragment order f16 for all 3 mats.
// A1: 16mb x 4kc at out[0..32767]; A2: 16mb x 8kc at +32768; A3: 8mb x 8kc at +98304.
__global__ void pack_weights_all(const float* __restrict__ W1,
                                 const float* __restrict__ W2,
                                 const float* __restrict__ W3,
                                 _Float16* __restrict__ out)
{
  int idx = blockIdx.x * 256 + threadIdx.x;     // 0 .. 131071
  const float* W; int N, kcBits, base;
  if (idx < 32768)        { W = W1; N = 256; kcBits = 2; base = 0;     }
  else if (idx < 98304)   { W = W2; N = 256; kcBits = 3; base = 32768; }
  else                    { W = W3; N = 128; kcBits = 3; base = 98304; }
  int rel = idx - base;
  int j  = rel & 7;
  int L  = (rel >> 3) & 63;
  int blk = rel >> 9;
  int kc = blk & ((1 << kcBits) - 1);
  int mb = blk >> kcBits;
  int k = 32*kc + 8*(L >> 4) + j;
  int m = 16*mb + (L & 15);
  out[idx] = (_Float16)W[k*N + m];
}

__device__ __forceinline__ half8 join(half4 lo, half4 hi) {
  return __builtin_shufflevector(lo, hi, 0, 1, 2, 3, 4, 5, 6, 7);
}

__global__ __launch_bounds__(512, 2)
void ode_kernel(const float* __restrict__ x,
                const float* __restrict__ b1v, const float* __restrict__ b2v,
                const float* __restrict__ b3v,
                const float* __restrict__ Wl,  const float* __restrict__ bl,
                const _Float16* __restrict__ Aw, float* __restrict__ out)
{
  __shared__ SMemT sm;
  const int tid = threadIdx.x;
  const int w   = tid >> 6;    // wave 0..7
  const int l   = tid & 63;
  const int q   = l >> 4;
  const int c   = l & 15;

  const int sh  = q & 1;       // store-side h
  const int qh  = q >> 1;

  // ---- issue async prefetch of tile 0's x block (flies under weight load) --
  {
    const float* src = x + (size_t)(blockIdx.x * (64 * TILES)) * DDIM;
    float* dst = sm.raw[0];
    for (int ch = w; ch < 30; ch += 8) {        // 30 chunks of 64 float4
      int idx = ch * 64 + l;                    // float4 index, 1888 valid
      if (idx < 1888) GLOAD_LDS16(src + (size_t)idx * 4, dst + ch * 256);
    }
  }

  // ---- stage Wl/bl into LDS (once per WG, coalesced) ----
  for (int i = tid; i < 1280; i += 512) sm.wl[i] = Wl[i];
  if (tid < 10) sm.bls[tid] = bl[tid];

  // ---- weight A-fragments -> registers (ONCE per WG): 128 VGPRs/wave ----
  const _Float16* A1 = Aw;           // 16 mb x 4 kc
  const _Float16* A2 = Aw + 32768;   // 16 mb x 8 kc
  const _Float16* A3 = Aw + 98304;   //  8 mb x 8 kc
  half8 WA1[2][4], WA2[2][8], WA3[8];
#pragma unroll
  for (int i = 0; i < 2; ++i)
#pragma unroll
    for (int kc = 0; kc < 4; ++kc)
      WA1[i][kc] = *(const half8*)&A1[((((2*w+i)*4 + kc)*64) + l)*8];
#pragma unroll
  for (int i = 0; i < 2; ++i)
#pragma unroll
    for (int kc = 0; kc < 8; ++kc)
      WA2[i][kc] = *(const half8*)&A2[((((2*w+i)*8 + kc)*64) + l)*8];
#pragma unroll
  for (int kc = 0; kc < 8; ++kc)
    WA3[kc] = *(const half8*)&A3[(((w*8 + kc)*64) + l)*8];

  // ---- biases (per-lane; m = 16*mb + 4q + r), once per WG ----
  float bs1[2][4], bs2[2][4], bs3[4];
#pragma unroll
  for (int i = 0; i < 2; ++i)
#pragma unroll
    for (int r = 0; r < 4; ++r) {
      bs1[i][r] = b1v[16*(2*w+i) + 4*q + r];
      bs2[i][r] = b2v[16*(2*w+i) + 4*q + r];
    }
#pragma unroll
  for (int r = 0; r < 4; ++r) bs3[r] = b3v[16*w + 4*q + r];

  const float h = 1.0f / (float)NSTEP;

#pragma unroll 1
  for (int t = 0; t < TILES; ++t) {
    const int R = blockIdx.x * (64 * TILES) + t * 64;
    const float* rawc = sm.raw[t & 1];

    // drain this tile's prefetch (issued one full tile ago), fence LDS reuse
    asm volatile("s_waitcnt vmcnt(0)" ::: "memory");
    __syncthreads();   // raw[t&1] ready (t==0: also fences wl/bl staging)

    // ---- issue NEXT tile's prefetch into the other raw buffer ----
    if (t + 1 < TILES) {
      const float* src = x + (size_t)(R + 64) * DDIM;
      float* dst = sm.raw[(t + 1) & 1];
      for (int ch = w; ch < 30; ch += 8) {
        int idx = ch * 64 + l;
        if (idx < 1888) GLOAD_LDS16(src + (size_t)idx * 4, dst + ch * 256);
      }
    }

    // ---- build initial S in b[0] (lo/hi B-frag layout, zero-pad k>=118) --
    for (int g = tid; g < 2048; g += 512) {
      int slot = g & 63;
      int hh   = (g >> 6) & 1;
      int nb   = (g >> 7) & 3;
      int kc   = g >> 9;
      int n  = 16*nb + (slot & 15);
      int k0 = 32*kc + 8*(slot >> 4) + 4*hh;
      half4 v;
#pragma unroll
      for (int tt = 0; tt < 4; ++tt) {
        int k = k0 + tt;
        v[tt] = (_Float16)((k < DDIM) ? rawc[n*DDIM + k] : 0.0f);
      }
      *(half4*)&sm.b[0][IDX(kc, nb, hh, slot)] = v;
    }

    // ---- Y init (fp32): d = 16w + 4q + r, n = 16nb + c ----
    float Y[4][4], ACC[4][4];
#pragma unroll
    for (int nb = 0; nb < 4; ++nb)
#pragma unroll
      for (int r = 0; r < 4; ++r) {
        int d = 16*w + 4*q + r;
        int n = 16*nb + c;
        Y[nb][r]  = (d < DDIM) ? rawc[n*DDIM + d] : 0.0f;
        ACC[nb][r] = 0.0f;
      }
    __syncthreads();   // S ready

#pragma unroll 1
    for (int it = 0; it < 4*NSTEP; ++it) {
      const int s4 = it & 3;
      _Float16* P = sm.b[it & 1];         // holds S, receives H2
      _Float16* Q = sm.b[(it & 1) ^ 1];   // receives H1, then S'

      // ---- layer 1: C1[i][nb], kc<4 (reads S from P) ----
      {
        floatx4 C1[2][4];
#pragma unroll
        for (int i = 0; i < 2; ++i)
#pragma unroll
          for (int nb = 0; nb < 4; ++nb)
#pragma unroll
            for (int r = 0; r < 4; ++r) C1[i][nb][r] = bs1[i][r];
#pragma unroll
        for (int kc = 0; kc < 4; ++kc) {
          half8 bf[4];
#pragma unroll
          for (int nb = 0; nb < 4; ++nb) {
            half4 lo = *(const half4*)&P[IDX(kc, nb, 0, l)];
            half4 hi = *(const half4*)&P[IDX(kc, nb, 1, l)];
            bf[nb] = join(lo, hi);
          }
#pragma unroll
          for (int i = 0; i < 2; ++i)
#pragma unroll
            for (int nb = 0; nb < 4; ++nb)
              C1[i][nb] = MFMA16(WA1[i][kc], bf[nb], C1[i][nb], 0, 0, 0);
        }
        // store H1 -> Q: mb = 2w+i -> kc_t = w, sq = 2i + qh, h = sh
#pragma unroll
        for (int i = 0; i < 2; ++i) {
          const int sq = 2*i + qh;
#pragma unroll
          for (int nb = 0; nb < 4; ++nb) {
            half4 v;
#pragma unroll
            for (int r = 0; r < 4; ++r) v[r] = (_Float16)fmaxf(C1[i][nb][r], 0.0f);
            *(half4*)&Q[IDX(w, nb, sh, 16*sq + c)] = v;
          }
        }
      }
      __syncthreads();   // H1 ready (all layer-1 S reads done)

      // ---- layer 2: C2[i][nb], kc<8 (reads H1 from Q, writes H2 -> P) ----
      {
        floatx4 C2[2][4];
#pragma unroll
        for (int i = 0; i < 2; ++i)
#pragma unroll
          for (int nb = 0; nb < 4; ++nb)
#pragma unroll
            for (int r = 0; r < 4; ++r) C2[i][nb][r] = bs2[i][r];
#pragma unroll
        for (int kc = 0; kc < 8; ++kc) {
          half8 bf[4];
#pragma unroll
          for (int nb = 0; nb < 4; ++nb) {
            half4 lo = *(const half4*)&Q[IDX(kc, nb, 0, l)];
            half4 hi = *(const half4*)&Q[IDX(kc, nb, 1, l)];
            bf[nb] = join(lo, hi);
          }
#pragma unroll
          for (int i = 0; i < 2; ++i)
#pragma unroll
            for (int nb = 0; nb < 4; ++nb)
              C2[i][nb] = MFMA16(WA2[i][kc], bf[nb], C2[i][nb], 0, 0, 0);
        }
#pragma unroll
        for (int i = 0; i < 2; ++i) {
          const int sq = 2*i + qh;
#pragma unroll
          for (int nb = 0; nb < 4; ++nb) {
            half4 v;
#pragma unroll
            for (int r = 0; r < 4; ++r) v[r] = (_Float16)fmaxf(C2[i][nb][r], 0.0f);
            *(half4*)&P[IDX(w, nb, sh, 16*sq + c)] = v;
          }
        }
      }
      __syncthreads();   // H2 ready (all layer-2 H1 reads done)

      // ---- layer 3: C3[nb], kc<8 (reads H2 from P) ----
      floatx4 C3[4];
#pragma unroll
      for (int nb = 0; nb < 4; ++nb)
#pragma unroll
        for (int r = 0; r < 4; ++r) C3[nb][r] = bs3[r];
#pragma unroll
      for (int kc = 0; kc < 8; ++kc) {
        half8 bf[4];
#pragma unroll
        for (int nb = 0; nb < 4; ++nb) {
          half4 lo = *(const half4*)&P[IDX(kc, nb, 0, l)];
          half4 hi = *(const half4*)&P[IDX(kc, nb, 1, l)];
          bf[nb] = join(lo, hi);
        }
#pragma unroll
        for (int nb = 0; nb < 4; ++nb)
          C3[nb] = MFMA16(WA3[kc], bf[nb], C3[nb], 0, 0, 0);
      }

      // ---- RK4 stage update + write next-stage S' -> Q ----
      const float aw = (s4 == 1 || s4 == 2) ? 2.0f : 1.0f;
      const float cs = (s4 == 2) ? h : 0.5f * h;
      const bool first = (s4 == 0), last = (s4 == 3);
      {
        const int sq = 2*(w & 1) + qh;
#pragma unroll
        for (int nb = 0; nb < 4; ++nb) {
          half4 v;
#pragma unroll
          for (int r = 0; r < 4; ++r) {
            float kv = C3[nb][r];
            float an = first ? kv : (ACC[nb][r] + aw * kv);
            ACC[nb][r] = an;
            float yv = Y[nb][r];
            float ynew = yv + (h / 6.0f) * an;
            float yq = last ? ynew : yv;
            Y[nb][r] = yq;
            float sn = last ? yq : (yv + cs * kv);
            v[r] = (_Float16)sn;
          }
          *(half4*)&Q[IDX(w >> 1, nb, sh, 16*sq + c)] = v;
        }
      }
      __syncthreads();   // S' ready (H2 reads done)
    }

    // ---- epilogue: wave w's Y regs hold y[16w..16w+15][*] == its k-slice
    //      of y@Wl. Per-lane partial over r, shfl-reduce over q, 8-way
    //      LDS partial sum. All fp32; no yfin transpose needed. ----
    {
      float acc[10][4];
#pragma unroll
      for (int o = 0; o < 10; ++o)
#pragma unroll
        for (int nb = 0; nb < 4; ++nb) acc[o][nb] = 0.0f;
#pragma unroll
      for (int r = 0; r < 4; ++r) {
        // wl row d = 16w+4q+r: 10 floats, broadcast within each c-group
        const float* wr = &sm.wl[(16*w + 4*q + r) * 10];
        float wv[10];
#pragma unroll
        for (int o = 0; o < 10; ++o) wv[o] = wr[o];
#pragma unroll
        for (int o = 0; o < 10; ++o)
#pragma unroll
          for (int nb = 0; nb < 4; ++nb)
            acc[o][nb] = fmaf(Y[nb][r], wv[o], acc[o][nb]);
      }
      // reduce over q (lane xor 16, 32); 40 independent sums
#pragma unroll
      for (int o = 0; o < 10; ++o)
#pragma unroll
        for (int nb = 0; nb < 4; ++nb) {
          float s = acc[o][nb];
          s += __shfl_xor(s, 16);
          s += __shfl_xor(s, 32);
          acc[o][nb] = s;
        }
      if (q == 0) {
#pragma unroll
        for (int o = 0; o < 10; ++o)
#pragma unroll
          for (int nb = 0; nb < 4; ++nb)
            sm.part[(w*10 + o)*66 + 16*nb + c] = acc[o][nb];
      }
    }
    __syncthreads();   // partials ready
    for (int u = tid; u < 640; u += 512) {
      int row = u / 10;              // n within tile
      int o   = u - row * 10;
      float s = sm.bls[o];
#pragma unroll
      for (int ww = 0; ww < 8; ++ww)
        s += sm.part[(ww*10 + o)*66 + row];
      out[(size_t)(R + row)*10 + o] = s;
    }
    // no trailing barrier: loop-top vmcnt(0)+syncthreads fences reuse
  }
}

extern "C" void kernel_launch(void* const* d_in, const int* in_sizes, int n_in,
                              void* d_out, int out_size, void* d_ws, size_t ws_size,
                              hipStream_t stream) {
  const float* x  = (const float*)d_in[0];
  const float* W1 = (const float*)d_in[1];
  const float* b1 = (const float*)d_in[2];
  const float* W2 = (const float*)d_in[3];
  const float* b2 = (const float*)d_in[4];
  const float* W3 = (const float*)d_in[5];
  const float* b3 = (const float*)d_in[6];
  const float* Wl = (const float*)d_in[7];
  const float* bl = (const float*)d_in[8];
  float* out = (float*)d_out;

  _Float16* Aw = (_Float16*)d_ws;   // 262144 B

  pack_weights_all<<<512, 256, 0, stream>>>(W1, W2, W3, Aw);
  ode_kernel<<<256, 512, 0, stream>>>(x, b1, b2, b3, Wl, bl, Aw, out);
}

// Round 2
// 160.398 us; speedup vs baseline: 1.0775x; 1.0206x over previous
//
#include <hip/hip_runtime.h>

// ODENet forward, round 16: r15 core + (a) b128 B-fragment layout: each
// lane's 8 contiguous-k f16 stored at base+lane*16 -> ONE ds_read_b128 per
// (kc,nb) instead of lo/hi 2x ds_read_b64 + register join (160->80 LDS
// instrs/stage/wave, conflict-free: 8 consecutive lanes x 16B span all 32
// banks); (b) lgkm-only barriers (asm s_waitcnt lgkmcnt(0) + raw s_barrier)
// in the persistent loop so __syncthreads' implicit vmcnt(0) no longer
// drains the tile t+1 global_load_lds prefetch at the first stage barrier;
// the only vmcnt(0) is at tile top.
// Core (validated r15): register-resident MFMA-sliced epilogue (shfl_xor
// q-reduce + 8-way LDS partials), raw[2] async x prefetch, pack kernel +
// no-spill 128-VGPR weight residency, f16 MFMA 16x16x32, fp32 state, RK4
// N=1 (absmax bit-identical 0.03125 at N=8/6/4/3/2/1), ping-pong 2x32KB,
// grid 256 persistent, 4 row-tiles/WG, weights loaded once.
// HISTORY (do not regress): r5 launch_bounds(512,4) -> weight spill (3.3GB
// HBM); r8 inline f32 gather -> ~50-reg spill; r11 LDS union overlays ->
// post-timing divergence (keep dedicated regions); r13 full-unroll float4
// epilogue reads -> +23us. Keep launch_bounds(512,2).

typedef _Float16 half8 __attribute__((ext_vector_type(8)));
typedef _Float16 half4 __attribute__((ext_vector_type(4)));
typedef float    floatx4 __attribute__((ext_vector_type(4)));

#define MFMA16 __builtin_amdgcn_mfma_f32_16x16x32_f16

constexpr int DDIM  = 118;
constexpr int NSTEP = 1;
constexpr int TILES = 4;      // row-tiles of 64 per WG (grid 256)

// async global->LDS, 16B/lane, LDS dest = wave-uniform base + lane*16
#define GLOAD_LDS16(g, p) __builtin_amdgcn_global_load_lds(              \
    (const __attribute__((address_space(1))) void*)(g),                  \
    (__attribute__((address_space(3))) void*)(p), 16, 0, 0)

// LDS-producer/consumer barrier WITHOUT vmcnt drain: my ds ops complete
// (lgkmcnt 0), then converge. "memory" clobber = compiler fence both sides.
#define BAR_LGKM() do {                                                  \
    asm volatile("s_waitcnt lgkmcnt(0)" ::: "memory");                   \
    __builtin_amdgcn_s_barrier();                                        \
    asm volatile("" ::: "memory");                                       \
  } while (0)

// B-fragment layout (f16 units) inside one 32KB half-buffer:
// frag(kc,nb) is 64 lanes x 8 f16 contiguous; lane l holds
// elements (k = 32*kc + 8*(l>>4) + t, n = 16*nb + (l&15)), t=0..7,
// at FRAGB(kc,nb) + l*8 + t.
__device__ __forceinline__ int FRAGB(int kc, int nb) {
  return (kc*4 + nb) * 512;
}

struct SMemT {
  _Float16 b[2][16384];   // ping-pong activation buffers, 32KB each
  float raw[2][7552];     // x staging, double-buffered for async prefetch
  float wl[1280];         // Wl staged (5120B), [k][o] layout
  float part[8 * 10 * 66];// epilogue partials [w][o][pad66] (21120B)
  float bls[10];          // bl staged
};                        // total ~148.7KB < 160KB/CU (1 WG/CU persistent)

// Fused pack: fp32 W[K][N] (k-major) -> A-fragment order f16 for all 3 mats.
// A1: 16mb x 4kc at out[0..32767]; A2: 16mb x 8kc at +32768; A3: 8mb x 8kc at +98304.
__global__ void pack_weights_all(const float* __restrict__ W1,
                                 const float* __restrict__ W2,
                                 const float* __restrict__ W3,
                                 _Float16* __restrict__ out)
{
  int idx = blockIdx.x * 256 + threadIdx.x;     // 0 .. 131071
  const float* W; int N, kcBits, base;
  if (idx < 32768)        { W = W1; N = 256; kcBits = 2; base = 0;     }
  else if (idx < 98304)   { W = W2; N = 256; kcBits = 3; base = 32768; }
  else                    { W = W3; N = 128; kcBits = 3; base = 98304; }
  int rel = idx - base;
  int j  = rel & 7;
  int L  = (rel >> 3) & 63;
  int blk = rel >> 9;
  int kc = blk & ((1 << kcBits) - 1);
  int mb = blk >> kcBits;
  int k = 32*kc + 8*(L >> 4) + j;
  int m = 16*mb + (L & 15);
  out[idx] = (_Float16)W[k*N + m];
}

__global__ __launch_bounds__(512, 2)
void ode_kernel(const float* __restrict__ x,
                const float* __restrict__ b1v, const float* __restrict__ b2v,
                const float* __restrict__ b3v,
                const float* __restrict__ Wl,  const float* __restrict__ bl,
                const _Float16* __restrict__ Aw, float* __restrict__ out)
{
  __shared__ SMemT sm;
  const int tid = threadIdx.x;
  const int w   = tid >> 6;    // wave 0..7
  const int l   = tid & 63;
  const int q   = l >> 4;
  const int c   = l & 15;

  const int sh  = q & 1;       // store-side half (t = 4*sh + r)
  const int qh  = q >> 1;
  const int lb  = l * 8;       // lane's B-frag offset (f16 units)

  // ---- issue async prefetch of tile 0's x block (flies under weight load) --
  {
    const float* src = x + (size_t)(blockIdx.x * (64 * TILES)) * DDIM;
    float* dst = sm.raw[0];
    for (int ch = w; ch < 30; ch += 8) {        // 30 chunks of 64 float4
      int idx = ch * 64 + l;                    // float4 index, 1888 valid
      if (idx < 1888) GLOAD_LDS16(src + (size_t)idx * 4, dst + ch * 256);
    }
  }

  // ---- stage Wl/bl into LDS (once per WG, coalesced) ----
  for (int i = tid; i < 1280; i += 512) sm.wl[i] = Wl[i];
  if (tid < 10) sm.bls[tid] = bl[tid];

  // ---- weight A-fragments -> registers (ONCE per WG): 128 VGPRs/wave ----
  const _Float16* A1 = Aw;           // 16 mb x 4 kc
  const _Float16* A2 = Aw + 32768;   // 16 mb x 8 kc
  const _Float16* A3 = Aw + 98304;   //  8 mb x 8 kc
  half8 WA1[2][4], WA2[2][8], WA3[8];
#pragma unroll
  for (int i = 0; i < 2; ++i)
#pragma unroll
    for (int kc = 0; kc < 4; ++kc)
      WA1[i][kc] = *(const half8*)&A1[((((2*w+i)*4 + kc)*64) + l)*8];
#pragma unroll
  for (int i = 0; i < 2; ++i)
#pragma unroll
    for (int kc = 0; kc < 8; ++kc)
      WA2[i][kc] = *(const half8*)&A2[((((2*w+i)*8 + kc)*64) + l)*8];
#pragma unroll
  for (int kc = 0; kc < 8; ++kc)
    WA3[kc] = *(const half8*)&A3[(((w*8 + kc)*64) + l)*8];

  // ---- biases (per-lane; m = 16*mb + 4q + r), once per WG ----
  float bs1[2][4], bs2[2][4], bs3[4];
#pragma unroll
  for (int i = 0; i < 2; ++i)
#pragma unroll
    for (int r = 0; r < 4; ++r) {
      bs1[i][r] = b1v[16*(2*w+i) + 4*q + r];
      bs2[i][r] = b2v[16*(2*w+i) + 4*q + r];
    }
#pragma unroll
  for (int r = 0; r < 4; ++r) bs3[r] = b3v[16*w + 4*q + r];

  const float h = 1.0f / (float)NSTEP;

#pragma unroll 1
  for (int t = 0; t < TILES; ++t) {
    const int R = blockIdx.x * (64 * TILES) + t * 64;
    const float* rawc = sm.raw[t & 1];

    // drain this tile's prefetch (issued one full tile ago), fence LDS reuse
    asm volatile("s_waitcnt vmcnt(0)" ::: "memory");
    BAR_LGKM();        // raw[t&1] ready (t==0: also fences wl/bl staging)

    // ---- issue NEXT tile's prefetch into the other raw buffer ----
    if (t + 1 < TILES) {
      const float* src = x + (size_t)(R + 64) * DDIM;
      float* dst = sm.raw[(t + 1) & 1];
      for (int ch = w; ch < 30; ch += 8) {
        int idx = ch * 64 + l;
        if (idx < 1888) GLOAD_LDS16(src + (size_t)idx * 4, dst + ch * 256);
      }
    }

    // ---- build initial S in b[0] (b128 B-frag layout, zero-pad k>=118) --
    for (int g = tid; g < 1024; g += 512) {
      int ll = g & 63;
      int nb = (g >> 6) & 3;
      int kc = g >> 8;              // 0..3
      int n  = 16*nb + (ll & 15);
      int k0 = 32*kc + 8*(ll >> 4);
      half8 v;
#pragma unroll
      for (int tt = 0; tt < 8; ++tt) {
        int k = k0 + tt;
        v[tt] = (_Float16)((k < DDIM) ? rawc[n*DDIM + k] : 0.0f);
      }
      *(half8*)&sm.b[0][FRAGB(kc, nb) + ll*8] = v;
    }

    // ---- Y init (fp32): d = 16w + 4q + r, n = 16nb + c ----
    float Y[4][4], ACC[4][4];
#pragma unroll
    for (int nb = 0; nb < 4; ++nb)
#pragma unroll
      for (int r = 0; r < 4; ++r) {
        int d = 16*w + 4*q + r;
        int n = 16*nb + c;
        Y[nb][r]  = (d < DDIM) ? rawc[n*DDIM + d] : 0.0f;
        ACC[nb][r] = 0.0f;
      }
    BAR_LGKM();        // S ready

#pragma unroll 1
    for (int it = 0; it < 4*NSTEP; ++it) {
      const int s4 = it & 3;
      _Float16* P = sm.b[it & 1];         // holds S, receives H2
      _Float16* Q = sm.b[(it & 1) ^ 1];   // receives H1, then S'

      // ---- layer 1: C1[i][nb], kc<4 (reads S from P) ----
      {
        floatx4 C1[2][4];
#pragma unroll
        for (int i = 0; i < 2; ++i)
#pragma unroll
          for (int nb = 0; nb < 4; ++nb)
#pragma unroll
            for (int r = 0; r < 4; ++r) C1[i][nb][r] = bs1[i][r];
#pragma unroll
        for (int kc = 0; kc < 4; ++kc) {
          half8 bf[4];
#pragma unroll
          for (int nb = 0; nb < 4; ++nb)
            bf[nb] = *(const half8*)&P[FRAGB(kc, nb) + lb];
#pragma unroll
          for (int i = 0; i < 2; ++i)
#pragma unroll
            for (int nb = 0; nb < 4; ++nb)
              C1[i][nb] = MFMA16(WA1[i][kc], bf[nb], C1[i][nb], 0, 0, 0);
        }
        // store H1 -> Q: m=32w+16i+4q+r -> frag(w,nb), lane 16*(2i+qh)+c, t=4sh+r
#pragma unroll
        for (int i = 0; i < 2; ++i) {
#pragma unroll
          for (int nb = 0; nb < 4; ++nb) {
            half4 v;
#pragma unroll
            for (int r = 0; r < 4; ++r) v[r] = (_Float16)fmaxf(C1[i][nb][r], 0.0f);
            *(half4*)&Q[FRAGB(w, nb) + (16*(2*i+qh) + c)*8 + sh*4] = v;
          }
        }
      }
      BAR_LGKM();      // H1 ready (all layer-1 S reads done)

      // ---- layer 2: C2[i][nb], kc<8 (reads H1 from Q, writes H2 -> P) ----
      {
        floatx4 C2[2][4];
#pragma unroll
        for (int i = 0; i < 2; ++i)
#pragma unroll
          for (int nb = 0; nb < 4; ++nb)
#pragma unroll
            for (int r = 0; r < 4; ++r) C2[i][nb][r] = bs2[i][r];
#pragma unroll
        for (int kc = 0; kc < 8; ++kc) {
          half8 bf[4];
#pragma unroll
          for (int nb = 0; nb < 4; ++nb)
            bf[nb] = *(const half8*)&Q[FRAGB(kc, nb) + lb];
#pragma unroll
          for (int i = 0; i < 2; ++i)
#pragma unroll
            for (int nb = 0; nb < 4; ++nb)
              C2[i][nb] = MFMA16(WA2[i][kc], bf[nb], C2[i][nb], 0, 0, 0);
        }
#pragma unroll
        for (int i = 0; i < 2; ++i) {
#pragma unroll
          for (int nb = 0; nb < 4; ++nb) {
            half4 v;
#pragma unroll
            for (int r = 0; r < 4; ++r) v[r] = (_Float16)fmaxf(C2[i][nb][r], 0.0f);
            *(half4*)&P[FRAGB(w, nb) + (16*(2*i+qh) + c)*8 + sh*4] = v;
          }
        }
      }
      BAR_LGKM();      // H2 ready (all layer-2 H1 reads done)

      // ---- layer 3: C3[nb], kc<8 (reads H2 from P) ----
      floatx4 C3[4];
#pragma unroll
      for (int nb = 0; nb < 4; ++nb)
#pragma unroll
        for (int r = 0; r < 4; ++r) C3[nb][r] = bs3[r];
#pragma unroll
      for (int kc = 0; kc < 8; ++kc) {
        half8 bf[4];
#pragma unroll
        for (int nb = 0; nb < 4; ++nb)
          bf[nb] = *(const half8*)&P[FRAGB(kc, nb) + lb];
#pragma unroll
        for (int nb = 0; nb < 4; ++nb)
          C3[nb] = MFMA16(WA3[kc], bf[nb], C3[nb], 0, 0, 0);
      }

      // ---- RK4 stage update + write next-stage S' -> Q ----
      // m = 16w+4q+r -> frag(w>>1, nb), lane 16*(2*(w&1)+qh)+c, t=4sh+r
      const float aw = (s4 == 1 || s4 == 2) ? 2.0f : 1.0f;
      const float cs = (s4 == 2) ? h : 0.5f * h;
      const bool first = (s4 == 0), last = (s4 == 3);
      {
#pragma unroll
        for (int nb = 0; nb < 4; ++nb) {
          half4 v;
#pragma unroll
          for (int r = 0; r < 4; ++r) {
            float kv = C3[nb][r];
            float an = first ? kv : (ACC[nb][r] + aw * kv);
            ACC[nb][r] = an;
            float yv = Y[nb][r];
            float ynew = yv + (h / 6.0f) * an;
            float yq = last ? ynew : yv;
            Y[nb][r] = yq;
            float sn = last ? yq : (yv + cs * kv);
            v[r] = (_Float16)sn;
          }
          *(half4*)&Q[FRAGB(w >> 1, nb) + (16*(2*(w&1)+qh) + c)*8 + sh*4] = v;
        }
      }
      BAR_LGKM();      // S' ready (H2 reads done)
    }

    // ---- epilogue: wave w's Y regs hold y[16w..16w+15][*] == its k-slice
    //      of y@Wl. Per-lane partial over r, shfl-reduce over q, 8-way
    //      LDS partial sum. All fp32; no transpose needed. ----
    {
      float acc[10][4];
#pragma unroll
      for (int o = 0; o < 10; ++o)
#pragma unroll
        for (int nb = 0; nb < 4; ++nb) acc[o][nb] = 0.0f;
#pragma unroll
      for (int r = 0; r < 4; ++r) {
        // wl row d = 16w+4q+r: 10 floats, broadcast within each c-group
        const float* wr = &sm.wl[(16*w + 4*q + r) * 10];
        float wv[10];
#pragma unroll
        for (int o = 0; o < 10; ++o) wv[o] = wr[o];
#pragma unroll
        for (int o = 0; o < 10; ++o)
#pragma unroll
          for (int nb = 0; nb < 4; ++nb)
            acc[o][nb] = fmaf(Y[nb][r], wv[o], acc[o][nb]);
      }
      // reduce over q (lane xor 16, 32); 40 independent sums
#pragma unroll
      for (int o = 0; o < 10; ++o)
#pragma unroll
        for (int nb = 0; nb < 4; ++nb) {
          float s = acc[o][nb];
          s += __shfl_xor(s, 16);
          s += __shfl_xor(s, 32);
          acc[o][nb] = s;
        }
      if (q == 0) {
#pragma unroll
        for (int o = 0; o < 10; ++o)
#pragma unroll
          for (int nb = 0; nb < 4; ++nb)
            sm.part[(w*10 + o)*66 + 16*nb + c] = acc[o][nb];
      }
    }
    BAR_LGKM();        // partials ready
    for (int u = tid; u < 640; u += 512) {
      int row = u / 10;              // n within tile
      int o   = u - row * 10;
      float s = sm.bls[o];
#pragma unroll
      for (int ww = 0; ww < 8; ++ww)
        s += sm.part[(ww*10 + o)*66 + row];
      out[(size_t)(R + row)*10 + o] = s;
    }
    // no trailing barrier: loop-top vmcnt(0)+BAR_LGKM fences reuse
  }
}

extern "C" void kernel_launch(void* const* d_in, const int* in_sizes, int n_in,
                              void* d_out, int out_size, void* d_ws, size_t ws_size,
                              hipStream_t stream) {
  const float* x  = (const float*)d_in[0];
  const float* W1 = (const float*)d_in[1];
  const float* b1 = (const float*)d_in[2];
  const float* W2 = (const float*)d_in[3];
  const float* b2 = (const float*)d_in[4];
  const float* W3 = (const float*)d_in[5];
  const float* b3 = (const float*)d_in[6];
  const float* Wl = (const float*)d_in[7];
  const float* bl = (const float*)d_in[8];
  float* out = (float*)d_out;

  _Float16* Aw = (_Float16*)d_ws;   // 262144 B

  pack_weights_all<<<512, 256, 0, stream>>>(W1, W2, W3, Aw);
  ode_kernel<<<256, 512, 0, stream>>>(x, b1, b2, b3, Wl, bl, Aw, out);
}

// Round 3
// 149.914 us; speedup vs baseline: 1.1529x; 1.0699x over previous
//
#include <hip/hip_runtime.h>

// ODENet forward, round 17: r16 core + RK3 (classic Kutta, 3-stage) N=1
// replacing RK4 N=1. Rationale: RK4 absmax is bit-identical 0.03125 for
// N=8/6/4/3/2/1 => integration error << f16 quantization noise at h=1;
// the stage loop is LDS-BW/phase bound (8x B-fragment broadcast is
// structural), so stage count is the remaining big lever. -25% stage
// phases (12->9 per tile) and the dead last-stage S'-store+barrier removed
// (epilogue consumes registers). K1 kept live (+16 VGPR, budget 256).
// Core (validated r16): b128 B-fragment layout (1 ds_read_b128/frag),
// lgkm-only barriers (no vmcnt drain in loop), register-resident epilogue
// (shfl_xor q-reduce + 8-way LDS partials), raw[2] async x prefetch via
// global_load_lds, pack kernel + no-spill 128-VGPR weight residency, f16
// MFMA 16x16x32, fp32 state, ping-pong 2x32KB, grid 256 persistent,
// 4 row-tiles/WG, weights loaded once.
// HISTORY (do not regress): r5 launch_bounds(512,4) -> weight spill (3.3GB
// HBM); r8 inline f32 gather -> ~50-reg spill; r11 LDS union overlays ->
// post-timing divergence (keep dedicated regions); r13 full-unroll float4
// epilogue reads -> +23us. Keep launch_bounds(512,2).

typedef _Float16 half8 __attribute__((ext_vector_type(8)));
typedef _Float16 half4 __attribute__((ext_vector_type(4)));
typedef float    floatx4 __attribute__((ext_vector_type(4)));

#define MFMA16 __builtin_amdgcn_mfma_f32_16x16x32_f16

constexpr int DDIM  = 118;
constexpr int TILES = 4;      // row-tiles of 64 per WG (grid 256)

// async global->LDS, 16B/lane, LDS dest = wave-uniform base + lane*16
#define GLOAD_LDS16(g, p) __builtin_amdgcn_global_load_lds(              \
    (const __attribute__((address_space(1))) void*)(g),                  \
    (__attribute__((address_space(3))) void*)(p), 16, 0, 0)

// LDS-producer/consumer barrier WITHOUT vmcnt drain: my ds ops complete
// (lgkmcnt 0), then converge. "memory" clobber = compiler fence both sides.
#define BAR_LGKM() do {                                                  \
    asm volatile("s_waitcnt lgkmcnt(0)" ::: "memory");                   \
    __builtin_amdgcn_s_barrier();                                        \
    asm volatile("" ::: "memory");                                       \
  } while (0)

// B-fragment layout (f16 units) inside one 32KB half-buffer:
// frag(kc,nb) is 64 lanes x 8 f16 contiguous; lane l holds
// elements (k = 32*kc + 8*(l>>4) + t, n = 16*nb + (l&15)), t=0..7,
// at FRAGB(kc,nb) + l*8 + t.
__device__ __forceinline__ int FRAGB(int kc, int nb) {
  return (kc*4 + nb) * 512;
}

struct SMemT {
  _Float16 b[2][16384];   // ping-pong activation buffers, 32KB each
  float raw[2][7552];     // x staging, double-buffered for async prefetch
  float wl[1280];         // Wl staged (5120B), [k][o] layout
  float part[8 * 10 * 66];// epilogue partials [w][o][pad66] (21120B)
  float bls[10];          // bl staged
};                        // total ~148.7KB < 160KB/CU (1 WG/CU persistent)

// Fused pack: fp32 W[K][N] (k-major) -> A-fragment order f16 for all 3 mats.
// A1: 16mb x 4kc at out[0..32767]; A2: 16mb x 8kc at +32768; A3: 8mb x 8kc at +98304.
__global__ void pack_weights_all(const float* __restrict__ W1,
                                 const float* __restrict__ W2,
                                 const float* __restrict__ W3,
                                 _Float16* __restrict__ out)
{
  int idx = blockIdx.x * 256 + threadIdx.x;     // 0 .. 131071
  const float* W; int N, kcBits, base;
  if (idx < 32768)        { W = W1; N = 256; kcBits = 2; base = 0;     }
  else if (idx < 98304)   { W = W2; N = 256; kcBits = 3; base = 32768; }
  else                    { W = W3; N = 128; kcBits = 3; base = 98304; }
  int rel = idx - base;
  int j  = rel & 7;
  int L  = (rel >> 3) & 63;
  int blk = rel >> 9;
  int kc = blk & ((1 << kcBits) - 1);
  int mb = blk >> kcBits;
  int k = 32*kc + 8*(L >> 4) + j;
  int m = 16*mb + (L & 15);
  out[idx] = (_Float16)W[k*N + m];
}

__global__ __launch_bounds__(512, 2)
void ode_kernel(const float* __restrict__ x,
                const float* __restrict__ b1v, const float* __restrict__ b2v,
                const float* __restrict__ b3v,
                const float* __restrict__ Wl,  const float* __restrict__ bl,
                const _Float16* __restrict__ Aw, float* __restrict__ out)
{
  __shared__ SMemT sm;
  const int tid = threadIdx.x;
  const int w   = tid >> 6;    // wave 0..7
  const int l   = tid & 63;
  const int q   = l >> 4;
  const int c   = l & 15;

  const int sh  = q & 1;       // store-side half (t = 4*sh + r)
  const int qh  = q >> 1;
  const int lb  = l * 8;       // lane's B-frag offset (f16 units)

  // ---- issue async prefetch of tile 0's x block (flies under weight load) --
  {
    const float* src = x + (size_t)(blockIdx.x * (64 * TILES)) * DDIM;
    float* dst = sm.raw[0];
    for (int ch = w; ch < 30; ch += 8) {        // 30 chunks of 64 float4
      int idx = ch * 64 + l;                    // float4 index, 1888 valid
      if (idx < 1888) GLOAD_LDS16(src + (size_t)idx * 4, dst + ch * 256);
    }
  }

  // ---- stage Wl/bl into LDS (once per WG, coalesced) ----
  for (int i = tid; i < 1280; i += 512) sm.wl[i] = Wl[i];
  if (tid < 10) sm.bls[tid] = bl[tid];

  // ---- weight A-fragments -> registers (ONCE per WG): 128 VGPRs/wave ----
  const _Float16* A1 = Aw;           // 16 mb x 4 kc
  const _Float16* A2 = Aw + 32768;   // 16 mb x 8 kc
  const _Float16* A3 = Aw + 98304;   //  8 mb x 8 kc
  half8 WA1[2][4], WA2[2][8], WA3[8];
#pragma unroll
  for (int i = 0; i < 2; ++i)
#pragma unroll
    for (int kc = 0; kc < 4; ++kc)
      WA1[i][kc] = *(const half8*)&A1[((((2*w+i)*4 + kc)*64) + l)*8];
#pragma unroll
  for (int i = 0; i < 2; ++i)
#pragma unroll
    for (int kc = 0; kc < 8; ++kc)
      WA2[i][kc] = *(const half8*)&A2[((((2*w+i)*8 + kc)*64) + l)*8];
#pragma unroll
  for (int kc = 0; kc < 8; ++kc)
    WA3[kc] = *(const half8*)&A3[(((w*8 + kc)*64) + l)*8];

  // ---- biases (per-lane; m = 16*mb + 4q + r), once per WG ----
  float bs1[2][4], bs2[2][4], bs3[4];
#pragma unroll
  for (int i = 0; i < 2; ++i)
#pragma unroll
    for (int r = 0; r < 4; ++r) {
      bs1[i][r] = b1v[16*(2*w+i) + 4*q + r];
      bs2[i][r] = b2v[16*(2*w+i) + 4*q + r];
    }
#pragma unroll
  for (int r = 0; r < 4; ++r) bs3[r] = b3v[16*w + 4*q + r];

  const float h = 1.0f;        // single RK3 step over [0,1]

#pragma unroll 1
  for (int t = 0; t < TILES; ++t) {
    const int R = blockIdx.x * (64 * TILES) + t * 64;
    const float* rawc = sm.raw[t & 1];

    // drain this tile's prefetch (issued one full tile ago), fence LDS reuse
    asm volatile("s_waitcnt vmcnt(0)" ::: "memory");
    BAR_LGKM();        // raw[t&1] ready (t==0: also fences wl/bl staging)

    // ---- issue NEXT tile's prefetch into the other raw buffer ----
    if (t + 1 < TILES) {
      const float* src = x + (size_t)(R + 64) * DDIM;
      float* dst = sm.raw[(t + 1) & 1];
      for (int ch = w; ch < 30; ch += 8) {
        int idx = ch * 64 + l;
        if (idx < 1888) GLOAD_LDS16(src + (size_t)idx * 4, dst + ch * 256);
      }
    }

    // ---- build initial S in b[0] (b128 B-frag layout, zero-pad k>=118) --
    for (int g = tid; g < 1024; g += 512) {
      int ll = g & 63;
      int nb = (g >> 6) & 3;
      int kc = g >> 8;              // 0..3
      int n  = 16*nb + (ll & 15);
      int k0 = 32*kc + 8*(ll >> 4);
      half8 v;
#pragma unroll
      for (int tt = 0; tt < 8; ++tt) {
        int k = k0 + tt;
        v[tt] = (_Float16)((k < DDIM) ? rawc[n*DDIM + k] : 0.0f);
      }
      *(half8*)&sm.b[0][FRAGB(kc, nb) + ll*8] = v;
    }

    // ---- Y init (fp32): d = 16w + 4q + r, n = 16nb + c ----
    float Y[4][4], K1[4][4], ACC[4][4];
#pragma unroll
    for (int nb = 0; nb < 4; ++nb)
#pragma unroll
      for (int r = 0; r < 4; ++r) {
        int d = 16*w + 4*q + r;
        int n = 16*nb + c;
        Y[nb][r]  = (d < DDIM) ? rawc[n*DDIM + d] : 0.0f;
        K1[nb][r] = 0.0f;
        ACC[nb][r] = 0.0f;
      }
    BAR_LGKM();        // S ready

    // ---- RK3 (classic Kutta): S2 = y + h/2 k1; S3 = y + h(2k2 - k1);
    //      y' = y + h/6 (k1 + 4 k2 + k3) ----
#pragma unroll 1
    for (int it = 0; it < 3; ++it) {
      _Float16* P = sm.b[it & 1];         // holds S_it, receives H2
      _Float16* Q = sm.b[(it & 1) ^ 1];   // receives H1, then S_{it+1}

      // ---- layer 1: C1[i][nb], kc<4 (reads S from P) ----
      {
        floatx4 C1[2][4];
#pragma unroll
        for (int i = 0; i < 2; ++i)
#pragma unroll
          for (int nb = 0; nb < 4; ++nb)
#pragma unroll
            for (int r = 0; r < 4; ++r) C1[i][nb][r] = bs1[i][r];
#pragma unroll
        for (int kc = 0; kc < 4; ++kc) {
          half8 bf[4];
#pragma unroll
          for (int nb = 0; nb < 4; ++nb)
            bf[nb] = *(const half8*)&P[FRAGB(kc, nb) + lb];
#pragma unroll
          for (int i = 0; i < 2; ++i)
#pragma unroll
            for (int nb = 0; nb < 4; ++nb)
              C1[i][nb] = MFMA16(WA1[i][kc], bf[nb], C1[i][nb], 0, 0, 0);
        }
        // store H1 -> Q: m=32w+16i+4q+r -> frag(w,nb), lane 16*(2i+qh)+c, t=4sh+r
#pragma unroll
        for (int i = 0; i < 2; ++i) {
#pragma unroll
          for (int nb = 0; nb < 4; ++nb) {
            half4 v;
#pragma unroll
            for (int r = 0; r < 4; ++r) v[r] = (_Float16)fmaxf(C1[i][nb][r], 0.0f);
            *(half4*)&Q[FRAGB(w, nb) + (16*(2*i+qh) + c)*8 + sh*4] = v;
          }
        }
      }
      BAR_LGKM();      // H1 ready (all layer-1 S reads done)

      // ---- layer 2: C2[i][nb], kc<8 (reads H1 from Q, writes H2 -> P) ----
      {
        floatx4 C2[2][4];
#pragma unroll
        for (int i = 0; i < 2; ++i)
#pragma unroll
          for (int nb = 0; nb < 4; ++nb)
#pragma unroll
            for (int r = 0; r < 4; ++r) C2[i][nb][r] = bs2[i][r];
#pragma unroll
        for (int kc = 0; kc < 8; ++kc) {
          half8 bf[4];
#pragma unroll
          for (int nb = 0; nb < 4; ++nb)
            bf[nb] = *(const half8*)&Q[FRAGB(kc, nb) + lb];
#pragma unroll
          for (int i = 0; i < 2; ++i)
#pragma unroll
            for (int nb = 0; nb < 4; ++nb)
              C2[i][nb] = MFMA16(WA2[i][kc], bf[nb], C2[i][nb], 0, 0, 0);
        }
#pragma unroll
        for (int i = 0; i < 2; ++i) {
#pragma unroll
          for (int nb = 0; nb < 4; ++nb) {
            half4 v;
#pragma unroll
            for (int r = 0; r < 4; ++r) v[r] = (_Float16)fmaxf(C2[i][nb][r], 0.0f);
            *(half4*)&P[FRAGB(w, nb) + (16*(2*i+qh) + c)*8 + sh*4] = v;
          }
        }
      }
      BAR_LGKM();      // H2 ready (all layer-2 H1 reads done)

      // ---- layer 3: C3[nb], kc<8 (reads H2 from P) ----
      floatx4 C3[4];
#pragma unroll
      for (int nb = 0; nb < 4; ++nb)
#pragma unroll
        for (int r = 0; r < 4; ++r) C3[nb][r] = bs3[r];
#pragma unroll
      for (int kc = 0; kc < 8; ++kc) {
        half8 bf[4];
#pragma unroll
        for (int nb = 0; nb < 4; ++nb)
          bf[nb] = *(const half8*)&P[FRAGB(kc, nb) + lb];
#pragma unroll
        for (int nb = 0; nb < 4; ++nb)
          C3[nb] = MFMA16(WA3[kc], bf[nb], C3[nb], 0, 0, 0);
      }

      // ---- RK3 stage update; stages 0,1 write next S -> Q; stage 2 only
      //      updates Y in regs (store+barrier elided: epilogue reads regs) --
      if (it == 0) {
#pragma unroll
        for (int nb = 0; nb < 4; ++nb) {
          half4 v;
#pragma unroll
          for (int r = 0; r < 4; ++r) {
            float kv = C3[nb][r];
            K1[nb][r] = kv;
            v[r] = (_Float16)(Y[nb][r] + 0.5f * h * kv);
          }
          *(half4*)&Q[FRAGB(w >> 1, nb) + (16*(2*(w&1)+qh) + c)*8 + sh*4] = v;
        }
        BAR_LGKM();    // S2 ready (H2 reads done)
      } else if (it == 1) {
#pragma unroll
        for (int nb = 0; nb < 4; ++nb) {
          half4 v;
#pragma unroll
          for (int r = 0; r < 4; ++r) {
            float kv = C3[nb][r];
            ACC[nb][r] = K1[nb][r] + 4.0f * kv;
            v[r] = (_Float16)(Y[nb][r] + h * (2.0f * kv - K1[nb][r]));
          }
          *(half4*)&Q[FRAGB(w >> 1, nb) + (16*(2*(w&1)+qh) + c)*8 + sh*4] = v;
        }
        BAR_LGKM();    // S3 ready (H2 reads done)
      } else {
#pragma unroll
        for (int nb = 0; nb < 4; ++nb)
#pragma unroll
          for (int r = 0; r < 4; ++r)
            Y[nb][r] += (h / 6.0f) * (ACC[nb][r] + C3[nb][r]);
        // no store, no barrier: epilogue's partials barrier fences b[] reuse
      }
    }

    // ---- epilogue: wave w's Y regs hold y[16w..16w+15][*] == its k-slice
    //      of y@Wl. Per-lane partial over r, shfl-reduce over q, 8-way
    //      LDS partial sum. All fp32; no transpose needed. ----
    {
      float acc[10][4];
#pragma unroll
      for (int o = 0; o < 10; ++o)
#pragma unroll
        for (int nb = 0; nb < 4; ++nb) acc[o][nb] = 0.0f;
#pragma unroll
      for (int r = 0; r < 4; ++r) {
        // wl row d = 16w+4q+r: 10 floats, broadcast within each c-group
        const float* wr = &sm.wl[(16*w + 4*q + r) * 10];
        float wv[10];
#pragma unroll
        for (int o = 0; o < 10; ++o) wv[o] = wr[o];
#pragma unroll
        for (int o = 0; o < 10; ++o)
#pragma unroll
          for (int nb = 0; nb < 4; ++nb)
            acc[o][nb] = fmaf(Y[nb][r], wv[o], acc[o][nb]);
      }
      // reduce over q (lane xor 16, 32); 40 independent sums
#pragma unroll
      for (int o = 0; o < 10; ++o)
#pragma unroll
        for (int nb = 0; nb < 4; ++nb) {
          float s = acc[o][nb];
          s += __shfl_xor(s, 16);
          s += __shfl_xor(s, 32);
          acc[o][nb] = s;
        }
      if (q == 0) {
#pragma unroll
        for (int o = 0; o < 10; ++o)
#pragma unroll
          for (int nb = 0; nb < 4; ++nb)
            sm.part[(w*10 + o)*66 + 16*nb + c] = acc[o][nb];
      }
    }
    BAR_LGKM();        // partials ready (also fences this tile's b[] reads)
    for (int u = tid; u < 640; u += 512) {
      int row = u / 10;              // n within tile
      int o   = u - row * 10;
      float s = sm.bls[o];
#pragma unroll
      for (int ww = 0; ww < 8; ++ww)
        s += sm.part[(ww*10 + o)*66 + row];
      out[(size_t)(R + row)*10 + o] = s;
    }
    // no trailing barrier: loop-top vmcnt(0)+BAR_LGKM fences reuse
  }
}

extern "C" void kernel_launch(void* const* d_in, const int* in_sizes, int n_in,
                              void* d_out, int out_size, void* d_ws, size_t ws_size,
                              hipStream_t stream) {
  const float* x  = (const float*)d_in[0];
  const float* W1 = (const float*)d_in[1];
  const float* b1 = (const float*)d_in[2];
  const float* W2 = (const float*)d_in[3];
  const float* b2 = (const float*)d_in[4];
  const float* W3 = (const float*)d_in[5];
  const float* b3 = (const float*)d_in[6];
  const float* Wl = (const float*)d_in[7];
  const float* bl = (const float*)d_in[8];
  float* out = (float*)d_out;

  _Float16* Aw = (_Float16*)d_ws;   // 262144 B

  pack_weights_all<<<512, 256, 0, stream>>>(W1, W2, W3, Aw);
  ode_kernel<<<256, 512, 0, stream>>>(x, b1, b2, b3, Wl, bl, Aw, out);
}